// Round 7
// baseline (276.372 us; speedup 1.0000x reference)
//
#include <hip/hip_runtime.h>

typedef __attribute__((ext_vector_type(8))) short short8;
typedef __attribute__((ext_vector_type(4))) short short4v;
typedef __attribute__((ext_vector_type(4))) float f32x4;

#define M_TOTAL 40770   // number of spans
#define NTOK    2048
#define HD      512
#define BM      64      // spans per block in main kernel

__device__ __forceinline__ short f2bf(float f) {
  unsigned u = __builtin_bit_cast(unsigned, f);
  u += 0x7FFFu + ((u >> 16) & 1u);
  return (short)(u >> 16);
}

// ---------------------------------------------------------------------------
// K1: embW[t] = concat(We_pos[tag], We_wrd[word]) @ dan_w0   [2048,512] fp32
// ---------------------------------------------------------------------------
__global__ void k_embW(const int* __restrict__ sentence, const int* __restrict__ pos_tags,
                       const float* __restrict__ We_wrd, const float* __restrict__ We_pos,
                       const float* __restrict__ dan_w0, float* __restrict__ embW) {
  __shared__ float rowf[8][512];   // 16 KB
  const int tid = threadIdx.x;
  const int b = blockIdx.x;
  for (int p = 0; p < 8; ++p) {
    int idx = p * 512 + tid;
    int m = idx >> 9, k = idx & 511;
    int tk = b * 8 + m;
    rowf[m][k] = (k < 256) ? We_pos[pos_tags[tk] * 256 + k]
                           : We_wrd[sentence[tk] * 256 + (k - 256)];
  }
  __syncthreads();
  float acc[8] = {0.f, 0.f, 0.f, 0.f, 0.f, 0.f, 0.f, 0.f};
  const int n = tid;
  for (int k4 = 0; k4 < 512; k4 += 4) {
    float w0 = dan_w0[(k4 + 0) * 512 + n];
    float w1 = dan_w0[(k4 + 1) * 512 + n];
    float w2 = dan_w0[(k4 + 2) * 512 + n];
    float w3 = dan_w0[(k4 + 3) * 512 + n];
#pragma unroll
    for (int m = 0; m < 8; ++m) {
      float4 rv = *(const float4*)&rowf[m][k4];
      acc[m] += rv.x * w0;
      acc[m] += rv.y * w1;
      acc[m] += rv.z * w2;
      acc[m] += rv.w * w3;
    }
  }
#pragma unroll
  for (int m = 0; m < 8; ++m)
    embW[(size_t)(b * 8 + m) * 512 + n] = acc[m];
}

// ---------------------------------------------------------------------------
// K2a/b/c: column-wise inclusive scan of embW (chunked 16 rows, 128 chunks)
// ---------------------------------------------------------------------------
__global__ void k_scan_a(const float* __restrict__ embW, float* __restrict__ cSum) {
  int b = blockIdx.x, t = threadIdx.x;
  int ch = b >> 1, cc = (b & 1) * 256 + t;
  float s = 0.f;
  for (int r = 0; r < 16; ++r) s += embW[(size_t)(ch * 16 + r) * 512 + cc];
  cSum[ch * 512 + cc] = s;
}
__global__ void k_scan_b(const float* __restrict__ cSum, float* __restrict__ cPre) {
  int cc = blockIdx.x * 256 + threadIdx.x;
  float run = 0.f;
  for (int ch = 0; ch < 128; ++ch) {
    cPre[ch * 512 + cc] = run;
    run += cSum[ch * 512 + cc];
  }
}
__global__ void k_scan_c(const float* __restrict__ embW, const float* __restrict__ cPre,
                         float* __restrict__ csumW) {
  int b = blockIdx.x, t = threadIdx.x;
  int ch = b >> 1, cc = (b & 1) * 256 + t;
  float run = cPre[ch * 512 + cc];
  if (ch == 0) csumW[cc] = 0.f;
  for (int r = 0; r < 16; ++r) {
    run += embW[(size_t)(ch * 16 + r) * 512 + cc];
    csumW[(size_t)(ch * 16 + r + 1) * 512 + cc] = run;
  }
}

// ---------------------------------------------------------------------------
// K3: pre-shuffle dan_w1, ws_w0[0:512], ws_w0[512:640] into MFMA
// B-fragment-linear bf16. Block b = one k-row (coalesced reads), thread = n.
// ---------------------------------------------------------------------------
__global__ void k_prepack(const float* __restrict__ dan_w1, const float* __restrict__ ws_w0,
                          short* __restrict__ w1_shuf, short* __restrict__ w0s_shuf,
                          short* __restrict__ w0pe_shuf) {
  const int k = blockIdx.x;     // 0..639
  const int n = threadIdx.x;    // 0..511
  const int g = (k >> 3) & 3, j = k & 7;
  if (k < 512) {
    int o = ((n >> 4) * 16 + (k >> 5)) * 512 + g * 128 + (n & 15) * 8 + j;
    w1_shuf[o] = f2bf(dan_w1[(size_t)k * 512 + n]);
    w0s_shuf[o] = f2bf(ws_w0[(size_t)k * 512 + n]);
  } else {
    int o2 = ((n >> 4) * 4 + ((k >> 5) - 16)) * 512 + g * 128 + (n & 15) * 8 + j;
    w0pe_shuf[o2] = f2bf(ws_w0[(size_t)k * 512 + n]);
  }
}

// One K=32 step of the 64x512 tile GEMM. SWAPPED=1 computes the transposed
// product (operands exchanged) with identical LDS reads / weight stream.
#define GEMM_STEP(WSH, KT_TOT, KT, SWAPPED)                                     \
  {                                                                             \
    short8 afr[4], bfr[4];                                                      \
    _Pragma("unroll") for (int mt_ = 0; mt_ < 4; ++mt_)                         \
      afr[mt_] = *(const short8*)(tileS + ((c + 16 * mt_) * 512 +               \
        ((((KT) * 64 + 16 * g) ^ ((c & 7) << 4)) >> 1)));                       \
    _Pragma("unroll") for (int i_ = 0; i_ < 4; ++i_)                            \
      bfr[i_] = ((const short8*)(WSH))[((4 * w + i_) * (KT_TOT) + (KT)) * 64 + lane]; \
    _Pragma("unroll") for (int i_ = 0; i_ < 4; ++i_) {                          \
      _Pragma("unroll") for (int mt_ = 0; mt_ < 4; ++mt_) {                     \
        if (SWAPPED)                                                            \
          acc[mt_][i_] = __builtin_amdgcn_mfma_f32_16x16x32_bf16(               \
              bfr[i_], afr[mt_], acc[mt_][i_], 0, 0, 0);                        \
        else                                                                    \
          acc[mt_][i_] = __builtin_amdgcn_mfma_f32_16x16x32_bf16(               \
              afr[mt_], bfr[i_], acc[mt_][i_], 0, 0, 0);                        \
      }                                                                         \
    }                                                                           \
  }

// ---------------------------------------------------------------------------
// K4: main fused kernel. 64 spans/block, 512 threads / 8 waves; wave w owns
// output cols [64w,64w+64). gemm1 swapped (phrase^T in acc -> packed b64
// phrase writes); PE-gemm runs register-only before the barrier; gemm2
// accumulates on top. LDS 64 KiB -> 2 blocks/CU.
// ---------------------------------------------------------------------------
__launch_bounds__(512, 4)
__global__ void k_main(const int* __restrict__ spans_start, const int* __restrict__ spans_len,
                       const float* __restrict__ csumW, const short* __restrict__ w1_shuf,
                       const short* __restrict__ w0s_shuf, const short* __restrict__ w0pe_shuf,
                       const float* __restrict__ b0, const float* __restrict__ b1,
                       const float* __restrict__ bs0, const float* __restrict__ ws_w1,
                       const float* __restrict__ ws_b1, float* __restrict__ out) {
  __shared__ short tileS[BM * 512];  // 64 KiB: holds h, then phrase, then scores

  const int tid = threadIdx.x;
  const int lane = tid & 63;
  const int w = tid >> 6;        // wave 0..7
  const int g = lane >> 4;       // 16-lane group 0..3
  const int c = lane & 15;

  // XCD-bijective block swizzle (m204)
  const int nwg = gridDim.x;
  const int q = nwg >> 3, r = nwg & 7;
  const int xcd = blockIdx.x & 7, sub = blockIdx.x >> 3;
  const int bid = (xcd < r ? xcd * (q + 1) : r * (q + 1) + (xcd - r) * q) + sub;
  const int cb = bid * BM;

  // ---- Phase 1: h[m][k] = relu((csumW[en]-csumW[st])*inv + b0[k]) -> tileS
  {
    const float4 bb0 = *(const float4*)(b0 + 8 * lane);
    const float4 bb1 = *(const float4*)(b0 + 8 * lane + 4);
    for (int rep = 0; rep < 8; ++rep) {
      int m = 8 * rep + w;  // wave-uniform row
      int ch = cb + m;
      if (ch >= M_TOTAL) ch = M_TOTAL - 1;
      int st = spans_start[ch];
      int ln = spans_len[ch];
      int en = st + ln;
      float inv = 1.0f / (float)ln;
      const float* pe_ = csumW + (size_t)en * 512 + 8 * lane;
      const float* ps_ = csumW + (size_t)st * 512 + 8 * lane;
      float4 e0 = *(const float4*)pe_, e1 = *(const float4*)(pe_ + 4);
      float4 s0 = *(const float4*)ps_, s1 = *(const float4*)(ps_ + 4);
      float hv[8];
      hv[0] = (e0.x - s0.x) * inv + bb0.x;
      hv[1] = (e0.y - s0.y) * inv + bb0.y;
      hv[2] = (e0.z - s0.z) * inv + bb0.z;
      hv[3] = (e0.w - s0.w) * inv + bb0.w;
      hv[4] = (e1.x - s1.x) * inv + bb1.x;
      hv[5] = (e1.y - s1.y) * inv + bb1.y;
      hv[6] = (e1.z - s1.z) * inv + bb1.z;
      hv[7] = (e1.w - s1.w) * inv + bb1.w;
      short8 hs;
#pragma unroll
      for (int j = 0; j < 8; ++j) hs[j] = f2bf(fmaxf(hv[j], 0.f));
      int idx = m * 512 + (((16 * lane) ^ ((m & 7) << 4)) >> 1);
      *(short8*)(tileS + idx) = hs;
    }
  }
  __syncthreads();

  const f32x4 zero4 = {0.f, 0.f, 0.f, 0.f};
  f32x4 acc[4][4];   // [mt][i] -> 64 AGPR

  // ---- Phase 2: phrase^T = relu(h @ w1 + b1)^T via swapped-operand MFMA
#pragma unroll
  for (int mt = 0; mt < 4; ++mt)
#pragma unroll
    for (int i = 0; i < 4; ++i) acc[mt][i] = zero4;
#pragma unroll
  for (int kt = 0; kt < 16; ++kt) GEMM_STEP(w1_shuf, 16, kt, 1)
  __syncthreads();  // all reads of h complete before overwriting tileS

  // acc[mt][i][r] = phrase_pre[m = c+16mt][n = 16*(4w+i) + 4g + r]
#pragma unroll
  for (int i = 0; i < 4; ++i) {
    const float4 b1v = *(const float4*)(b1 + 16 * (4 * w + i) + 4 * g);
#pragma unroll
    for (int mt = 0; mt < 4; ++mt) {
      short4v pk;
      pk[0] = f2bf(fmaxf(acc[mt][i][0] + b1v.x, 0.f));
      pk[1] = f2bf(fmaxf(acc[mt][i][1] + b1v.y, 0.f));
      pk[2] = f2bf(fmaxf(acc[mt][i][2] + b1v.z, 0.f));
      pk[3] = f2bf(fmaxf(acc[mt][i][3] + b1v.w, 0.f));
      int row = c + 16 * mt;
      int byteoff = (32 * (4 * w + i) + 8 * g) ^ ((c & 7) << 4);
      *(short4v*)((char*)tileS + row * 1024 + byteoff) = pk;
    }
  }

  // ---- Phase 3b (moved early): s_pre = feats @ ws_w0[512:640], register-only.
  // Runs before the barrier so sinf/MFMA overlap the LDS-write drain.
#pragma unroll
  for (int mt = 0; mt < 4; ++mt)
#pragma unroll
    for (int i = 0; i < 4; ++i) acc[mt][i] = zero4;
  {
    float x4v[4][4];
#pragma unroll
    for (int mt = 0; mt < 4; ++mt) {
      int ch = cb + c + 16 * mt;
      if (ch >= M_TOTAL) ch = M_TOTAL - 1;
      float st = (float)spans_start[ch];
      float ln = (float)spans_len[ch];
      x4v[mt][0] = st;
      x4v[mt][1] = st + ln;
      x4v[mt][2] = ln;
      x4v[mt][3] = st + 0.5f * ln;
    }
    float fr[8];
    float dbase = 8.0f * (float)(g & 1);
#pragma unroll
    for (int j = 0; j < 8; ++j)
      fr[j] = __expf(-0.5756462732485115f * (dbase + (float)j));  // ln(1e4)/16
    const float ph = (g >= 2) ? 1.5707963267948966f : 0.0f;
    const short8* Wpe = (const short8*)w0pe_shuf;
#pragma unroll
    for (int kt = 0; kt < 4; ++kt) {
      short8 af[4];
#pragma unroll
      for (int mt = 0; mt < 4; ++mt) {
#pragma unroll
        for (int j = 0; j < 8; ++j)
          af[mt][j] = f2bf(__sinf(x4v[mt][kt] * fr[j] + ph));
      }
#pragma unroll
      for (int i = 0; i < 4; ++i) {
        short8 bfrag = Wpe[((4 * w + i) * 4 + kt) * 64 + lane];
#pragma unroll
        for (int mt = 0; mt < 4; ++mt)
          acc[mt][i] = __builtin_amdgcn_mfma_f32_16x16x32_bf16(af[mt], bfrag, acc[mt][i], 0, 0, 0);
      }
    }
  }
  __syncthreads();  // phrase writes visible to all waves

  // ---- Phase 3a: acc += phrase @ ws_w0[0:512]  (unswapped)
#pragma unroll
  for (int kt = 0; kt < 16; ++kt) GEMM_STEP(w0s_shuf, 16, kt, 0)
  __syncthreads();  // phrase reads done; tileS reusable for score partials

  // ---- Phase 4: s = relu(s_pre + bs0); score = s . ws_w1
  float* scoreF = (float*)tileS;
  float bsv[4], w1v[4];
#pragma unroll
  for (int i = 0; i < 4; ++i) {
    int n = c + 16 * (4 * w + i);
    bsv[i] = bs0[n];
    w1v[i] = ws_w1[n];
  }
#pragma unroll
  for (int mt = 0; mt < 4; ++mt) {
#pragma unroll
    for (int r2 = 0; r2 < 4; ++r2) {
      int m = 16 * mt + 4 * g + r2;
      float p = 0.f;
#pragma unroll
      for (int i = 0; i < 4; ++i) {
        float v = acc[mt][i][r2] + bsv[i];
        p += fmaxf(v, 0.f) * w1v[i];
      }
      p += __shfl_xor(p, 1);
      p += __shfl_xor(p, 2);
      p += __shfl_xor(p, 4);
      p += __shfl_xor(p, 8);
      if (c == 0) scoreF[w * 64 + m] = p;
    }
  }
  __syncthreads();
  if (tid < 64) {
    int ch = cb + tid;
    if (ch < M_TOTAL) {
      float s = ws_b1[0];
#pragma unroll
      for (int ww = 0; ww < 8; ++ww) s += scoreF[ww * 64 + tid];
      out[ch] = s;
    }
  }
}

// ---------------------------------------------------------------------------
extern "C" void kernel_launch(void* const* d_in, const int* in_sizes, int n_in,
                              void* d_out, int out_size, void* d_ws, size_t ws_size,
                              hipStream_t stream) {
  const int* sentence = (const int*)d_in[0];
  const int* pos_tags = (const int*)d_in[1];
  const int* sp_start = (const int*)d_in[2];
  const int* sp_len   = (const int*)d_in[3];
  const float* We_wrd = (const float*)d_in[4];
  const float* We_pos = (const float*)d_in[5];
  const float* dan_w0 = (const float*)d_in[6];
  const float* dan_b0 = (const float*)d_in[7];
  const float* dan_w1 = (const float*)d_in[8];
  const float* dan_b1 = (const float*)d_in[9];
  const float* ws_w0  = (const float*)d_in[10];
  const float* ws_b0  = (const float*)d_in[11];
  const float* ws_w1  = (const float*)d_in[12];
  const float* ws_b1  = (const float*)d_in[13];
  float* out = (float*)d_out;

  char* ws = (char*)d_ws;
  float* embW     = (float*)(ws);              // 4,194,304 B
  float* csumW    = (float*)(ws + 4194304);    // 4,196,352 B
  float* cSum     = (float*)(ws + 8390656);    //   262,144 B
  float* cPre     = (float*)(ws + 8652800);    //   262,144 B
  short* w1_shuf  = (short*)(ws + 8914944);    //   524,288 B
  short* w0s_shuf = (short*)(ws + 9439232);    //   524,288 B
  short* w0pe_shuf= (short*)(ws + 9963520);    //   131,072 B -> total 10,094,592 B

  k_embW<<<256, 512, 0, stream>>>(sentence, pos_tags, We_wrd, We_pos, dan_w0, embW);
  k_scan_a<<<256, 256, 0, stream>>>(embW, cSum);
  k_scan_b<<<2, 256, 0, stream>>>(cSum, cPre);
  k_scan_c<<<256, 256, 0, stream>>>(embW, cPre, csumW);
  k_prepack<<<640, 512, 0, stream>>>(dan_w1, ws_w0, w1_shuf, w0s_shuf, w0pe_shuf);
  k_main<<<638, 512, 0, stream>>>(sp_start, sp_len, csumW, w1_shuf, w0s_shuf, w0pe_shuf,
                                  dan_b0, dan_b1, ws_b0, ws_w1, ws_b1, out);
}

// Round 8
// 248.759 us; speedup vs baseline: 1.1110x; 1.1110x over previous
//
#include <hip/hip_runtime.h>

typedef __attribute__((ext_vector_type(8))) short short8;
typedef __attribute__((ext_vector_type(4))) short short4v;
typedef __attribute__((ext_vector_type(4))) float f32x4;

#define M_TOTAL 40770   // number of spans
#define NTOK    2048
#define HD      512
#define BM      64      // spans per block in main kernel

__device__ __forceinline__ short f2bf(float f) {
  unsigned u = __builtin_bit_cast(unsigned, f);
  u += 0x7FFFu + ((u >> 16) & 1u);
  return (short)(u >> 16);
}

// ---------------------------------------------------------------------------
// K1: embW[t] = concat(We_pos[tag], We_wrd[word]) @ dan_w0   [2048,512] fp32
// ---------------------------------------------------------------------------
__global__ void k_embW(const int* __restrict__ sentence, const int* __restrict__ pos_tags,
                       const float* __restrict__ We_wrd, const float* __restrict__ We_pos,
                       const float* __restrict__ dan_w0, float* __restrict__ embW) {
  __shared__ float rowf[8][512];   // 16 KB
  const int tid = threadIdx.x;
  const int b = blockIdx.x;
  for (int p = 0; p < 8; ++p) {
    int idx = p * 512 + tid;
    int m = idx >> 9, k = idx & 511;
    int tk = b * 8 + m;
    rowf[m][k] = (k < 256) ? We_pos[pos_tags[tk] * 256 + k]
                           : We_wrd[sentence[tk] * 256 + (k - 256)];
  }
  __syncthreads();
  float acc[8] = {0.f, 0.f, 0.f, 0.f, 0.f, 0.f, 0.f, 0.f};
  const int n = tid;
  for (int k4 = 0; k4 < 512; k4 += 4) {
    float w0 = dan_w0[(k4 + 0) * 512 + n];
    float w1 = dan_w0[(k4 + 1) * 512 + n];
    float w2 = dan_w0[(k4 + 2) * 512 + n];
    float w3 = dan_w0[(k4 + 3) * 512 + n];
#pragma unroll
    for (int m = 0; m < 8; ++m) {
      float4 rv = *(const float4*)&rowf[m][k4];
      acc[m] += rv.x * w0;
      acc[m] += rv.y * w1;
      acc[m] += rv.z * w2;
      acc[m] += rv.w * w3;
    }
  }
#pragma unroll
  for (int m = 0; m < 8; ++m)
    embW[(size_t)(b * 8 + m) * 512 + n] = acc[m];
}

// ---------------------------------------------------------------------------
// K2a/b/c: column-wise inclusive scan of embW (chunked 16 rows, 128 chunks)
// ---------------------------------------------------------------------------
__global__ void k_scan_a(const float* __restrict__ embW, float* __restrict__ cSum) {
  int b = blockIdx.x, t = threadIdx.x;
  int ch = b >> 1, cc = (b & 1) * 256 + t;
  float s = 0.f;
  for (int r = 0; r < 16; ++r) s += embW[(size_t)(ch * 16 + r) * 512 + cc];
  cSum[ch * 512 + cc] = s;
}
__global__ void k_scan_b(const float* __restrict__ cSum, float* __restrict__ cPre) {
  int cc = blockIdx.x * 256 + threadIdx.x;
  float run = 0.f;
  for (int ch = 0; ch < 128; ++ch) {
    cPre[ch * 512 + cc] = run;
    run += cSum[ch * 512 + cc];
  }
}
__global__ void k_scan_c(const float* __restrict__ embW, const float* __restrict__ cPre,
                         float* __restrict__ csumW) {
  int b = blockIdx.x, t = threadIdx.x;
  int ch = b >> 1, cc = (b & 1) * 256 + t;
  float run = cPre[ch * 512 + cc];
  if (ch == 0) csumW[cc] = 0.f;
  for (int r = 0; r < 16; ++r) {
    run += embW[(size_t)(ch * 16 + r) * 512 + cc];
    csumW[(size_t)(ch * 16 + r + 1) * 512 + cc] = run;
  }
}

// ---------------------------------------------------------------------------
// K3: pre-shuffle dan_w1, ws_w0[0:512], ws_w0[512:640] into MFMA
// B-fragment-linear bf16. Block b = one k-row (coalesced reads), thread = n.
// ---------------------------------------------------------------------------
__global__ void k_prepack(const float* __restrict__ dan_w1, const float* __restrict__ ws_w0,
                          short* __restrict__ w1_shuf, short* __restrict__ w0s_shuf,
                          short* __restrict__ w0pe_shuf) {
  const int k = blockIdx.x;     // 0..639
  const int n = threadIdx.x;    // 0..511
  const int g = (k >> 3) & 3, j = k & 7;
  if (k < 512) {
    int o = ((n >> 4) * 16 + (k >> 5)) * 512 + g * 128 + (n & 15) * 8 + j;
    w1_shuf[o] = f2bf(dan_w1[(size_t)k * 512 + n]);
    w0s_shuf[o] = f2bf(ws_w0[(size_t)k * 512 + n]);
  } else {
    int o2 = ((n >> 4) * 4 + ((k >> 5) - 16)) * 512 + g * 128 + (n & 15) * 8 + j;
    w0pe_shuf[o2] = f2bf(ws_w0[(size_t)k * 512 + n]);
  }
}

// Round-4-proven register-lean GEMM loop: per kt load a[4] from LDS, then
// per-i a single weight fragment + 4 MFMAs. SWAPPED=1 computes the
// transposed product (operands exchanged), identical register footprint.
#define GEMM_LOOP(WSH, SWAPPED)                                                 \
  _Pragma("unroll 2")                                                           \
  for (int kt = 0; kt < 16; ++kt) {                                             \
    short8 a[4];                                                                \
    _Pragma("unroll") for (int mt_ = 0; mt_ < 4; ++mt_) {                       \
      int row_ = c + 16 * mt_;                                                  \
      int idx_ = row_ * 512 + (((kt * 64 + 16 * g) ^ ((c & 7) << 4)) >> 1);     \
      a[mt_] = *(const short8*)(tileS + idx_);                                  \
    }                                                                           \
    _Pragma("unroll") for (int i_ = 0; i_ < 4; ++i_) {                          \
      short8 bfrag = ((const short8*)(WSH))[((4 * w + i_) * 16 + kt) * 64 + lane]; \
      _Pragma("unroll") for (int mt_ = 0; mt_ < 4; ++mt_) {                     \
        if (SWAPPED)                                                            \
          acc[mt_][i_] = __builtin_amdgcn_mfma_f32_16x16x32_bf16(               \
              bfrag, a[mt_], acc[mt_][i_], 0, 0, 0);                            \
        else                                                                    \
          acc[mt_][i_] = __builtin_amdgcn_mfma_f32_16x16x32_bf16(               \
              a[mt_], bfrag, acc[mt_][i_], 0, 0, 0);                            \
      }                                                                         \
    }                                                                           \
  }

// ---------------------------------------------------------------------------
// K4: main fused kernel. 64 spans/block, 512 threads / 8 waves; wave w owns
// output cols [64w,64w+64). gemm1 swapped (phrase^T in acc -> packed b64
// phrase writes); PE-gemm register-only before the barrier; gemm2
// accumulates on top. LDS 64 KiB -> 2 blocks/CU, 4 waves/SIMD.
// ---------------------------------------------------------------------------
__launch_bounds__(512, 4)
__global__ void k_main(const int* __restrict__ spans_start, const int* __restrict__ spans_len,
                       const float* __restrict__ csumW, const short* __restrict__ w1_shuf,
                       const short* __restrict__ w0s_shuf, const short* __restrict__ w0pe_shuf,
                       const float* __restrict__ b0, const float* __restrict__ b1,
                       const float* __restrict__ bs0, const float* __restrict__ ws_w1,
                       const float* __restrict__ ws_b1, float* __restrict__ out) {
  __shared__ short tileS[BM * 512];  // 64 KiB: holds h, then phrase, then scores

  const int tid = threadIdx.x;
  const int lane = tid & 63;
  const int w = tid >> 6;        // wave 0..7
  const int g = lane >> 4;       // 16-lane group 0..3
  const int c = lane & 15;

  // XCD-bijective block swizzle (m204)
  const int nwg = gridDim.x;
  const int q = nwg >> 3, r = nwg & 7;
  const int xcd = blockIdx.x & 7, sub = blockIdx.x >> 3;
  const int bid = (xcd < r ? xcd * (q + 1) : r * (q + 1) + (xcd - r) * q) + sub;
  const int cb = bid * BM;

  // ---- Phase 1: h[m][k] = relu((csumW[en]-csumW[st])*inv + b0[k]) -> tileS
  {
    const float4 bb0 = *(const float4*)(b0 + 8 * lane);
    const float4 bb1 = *(const float4*)(b0 + 8 * lane + 4);
    for (int rep = 0; rep < 8; ++rep) {
      int m = 8 * rep + w;  // wave-uniform row
      int ch = cb + m;
      if (ch >= M_TOTAL) ch = M_TOTAL - 1;
      int st = spans_start[ch];
      int ln = spans_len[ch];
      int en = st + ln;
      float inv = 1.0f / (float)ln;
      const float* pe_ = csumW + (size_t)en * 512 + 8 * lane;
      const float* ps_ = csumW + (size_t)st * 512 + 8 * lane;
      float4 e0 = *(const float4*)pe_, e1 = *(const float4*)(pe_ + 4);
      float4 s0 = *(const float4*)ps_, s1 = *(const float4*)(ps_ + 4);
      float hv[8];
      hv[0] = (e0.x - s0.x) * inv + bb0.x;
      hv[1] = (e0.y - s0.y) * inv + bb0.y;
      hv[2] = (e0.z - s0.z) * inv + bb0.z;
      hv[3] = (e0.w - s0.w) * inv + bb0.w;
      hv[4] = (e1.x - s1.x) * inv + bb1.x;
      hv[5] = (e1.y - s1.y) * inv + bb1.y;
      hv[6] = (e1.z - s1.z) * inv + bb1.z;
      hv[7] = (e1.w - s1.w) * inv + bb1.w;
      short8 hs;
#pragma unroll
      for (int j = 0; j < 8; ++j) hs[j] = f2bf(fmaxf(hv[j], 0.f));
      int idx = m * 512 + (((16 * lane) ^ ((m & 7) << 4)) >> 1);
      *(short8*)(tileS + idx) = hs;
    }
  }
  __syncthreads();

  const f32x4 zero4 = {0.f, 0.f, 0.f, 0.f};
  f32x4 acc[4][4];   // [mt][i] -> 64 AGPR

  // ---- Phase 2: phrase^T = relu(h @ w1 + b1)^T via swapped-operand MFMA
#pragma unroll
  for (int mt = 0; mt < 4; ++mt)
#pragma unroll
    for (int i = 0; i < 4; ++i) acc[mt][i] = zero4;
  GEMM_LOOP(w1_shuf, 1)
  __syncthreads();  // all reads of h complete before overwriting tileS

  // acc[mt][i][r] = phrase_pre[m = c+16mt][n = 16*(4w+i) + 4g + r]
#pragma unroll
  for (int i = 0; i < 4; ++i) {
    const float4 b1v = *(const float4*)(b1 + 16 * (4 * w + i) + 4 * g);
#pragma unroll
    for (int mt = 0; mt < 4; ++mt) {
      short4v pk;
      pk[0] = f2bf(fmaxf(acc[mt][i][0] + b1v.x, 0.f));
      pk[1] = f2bf(fmaxf(acc[mt][i][1] + b1v.y, 0.f));
      pk[2] = f2bf(fmaxf(acc[mt][i][2] + b1v.z, 0.f));
      pk[3] = f2bf(fmaxf(acc[mt][i][3] + b1v.w, 0.f));
      int row = c + 16 * mt;
      int byteoff = (32 * (4 * w + i) + 8 * g) ^ ((c & 7) << 4);
      *(short4v*)((char*)tileS + row * 1024 + byteoff) = pk;
    }
  }

  // ---- Phase 3b (early): s_pre = feats @ ws_w0[512:640], register-only.
  // Runs before the barrier so sinf/MFMA overlap the LDS-write drain.
#pragma unroll
  for (int mt = 0; mt < 4; ++mt)
#pragma unroll
    for (int i = 0; i < 4; ++i) acc[mt][i] = zero4;
  {
    float x4v[4][4];
#pragma unroll
    for (int mt = 0; mt < 4; ++mt) {
      int ch = cb + c + 16 * mt;
      if (ch >= M_TOTAL) ch = M_TOTAL - 1;
      float st = (float)spans_start[ch];
      float ln = (float)spans_len[ch];
      x4v[mt][0] = st;
      x4v[mt][1] = st + ln;
      x4v[mt][2] = ln;
      x4v[mt][3] = st + 0.5f * ln;
    }
    float fr[8];
    float dbase = 8.0f * (float)(g & 1);
#pragma unroll
    for (int j = 0; j < 8; ++j)
      fr[j] = __expf(-0.5756462732485115f * (dbase + (float)j));  // ln(1e4)/16
    const float ph = (g >= 2) ? 1.5707963267948966f : 0.0f;
    const short8* Wpe = (const short8*)w0pe_shuf;
#pragma unroll 2
    for (int kt = 0; kt < 4; ++kt) {
      short8 af[4];
#pragma unroll
      for (int mt = 0; mt < 4; ++mt) {
#pragma unroll
        for (int j = 0; j < 8; ++j)
          af[mt][j] = f2bf(__sinf(x4v[mt][kt] * fr[j] + ph));
      }
#pragma unroll
      for (int i = 0; i < 4; ++i) {
        short8 bfrag = Wpe[((4 * w + i) * 4 + kt) * 64 + lane];
#pragma unroll
        for (int mt = 0; mt < 4; ++mt)
          acc[mt][i] = __builtin_amdgcn_mfma_f32_16x16x32_bf16(af[mt], bfrag, acc[mt][i], 0, 0, 0);
      }
    }
  }
  __syncthreads();  // phrase writes visible to all waves

  // ---- Phase 3a: acc += phrase @ ws_w0[0:512]  (unswapped)
  GEMM_LOOP(w0s_shuf, 0)
  __syncthreads();  // phrase reads done; tileS reusable for score partials

  // ---- Phase 4: s = relu(s_pre + bs0); score = s . ws_w1
  float* scoreF = (float*)tileS;
  float bsv[4], w1v[4];
#pragma unroll
  for (int i = 0; i < 4; ++i) {
    int n = c + 16 * (4 * w + i);
    bsv[i] = bs0[n];
    w1v[i] = ws_w1[n];
  }
#pragma unroll
  for (int mt = 0; mt < 4; ++mt) {
#pragma unroll
    for (int r2 = 0; r2 < 4; ++r2) {
      int m = 16 * mt + 4 * g + r2;
      float p = 0.f;
#pragma unroll
      for (int i = 0; i < 4; ++i) {
        float v = acc[mt][i][r2] + bsv[i];
        p += fmaxf(v, 0.f) * w1v[i];
      }
      p += __shfl_xor(p, 1);
      p += __shfl_xor(p, 2);
      p += __shfl_xor(p, 4);
      p += __shfl_xor(p, 8);
      if (c == 0) scoreF[w * 64 + m] = p;
    }
  }
  __syncthreads();
  if (tid < 64) {
    int ch = cb + tid;
    if (ch < M_TOTAL) {
      float s = ws_b1[0];
#pragma unroll
      for (int ww = 0; ww < 8; ++ww) s += scoreF[ww * 64 + tid];
      out[ch] = s;
    }
  }
}

// ---------------------------------------------------------------------------
extern "C" void kernel_launch(void* const* d_in, const int* in_sizes, int n_in,
                              void* d_out, int out_size, void* d_ws, size_t ws_size,
                              hipStream_t stream) {
  const int* sentence = (const int*)d_in[0];
  const int* pos_tags = (const int*)d_in[1];
  const int* sp_start = (const int*)d_in[2];
  const int* sp_len   = (const int*)d_in[3];
  const float* We_wrd = (const float*)d_in[4];
  const float* We_pos = (const float*)d_in[5];
  const float* dan_w0 = (const float*)d_in[6];
  const float* dan_b0 = (const float*)d_in[7];
  const float* dan_w1 = (const float*)d_in[8];
  const float* dan_b1 = (const float*)d_in[9];
  const float* ws_w0  = (const float*)d_in[10];
  const float* ws_b0  = (const float*)d_in[11];
  const float* ws_w1  = (const float*)d_in[12];
  const float* ws_b1  = (const float*)d_in[13];
  float* out = (float*)d_out;

  char* ws = (char*)d_ws;
  float* embW     = (float*)(ws);              // 4,194,304 B
  float* csumW    = (float*)(ws + 4194304);    // 4,196,352 B
  float* cSum     = (float*)(ws + 8390656);    //   262,144 B
  float* cPre     = (float*)(ws + 8652800);    //   262,144 B
  short* w1_shuf  = (short*)(ws + 8914944);    //   524,288 B
  short* w0s_shuf = (short*)(ws + 9439232);    //   524,288 B
  short* w0pe_shuf= (short*)(ws + 9963520);    //   131,072 B -> total 10,094,592 B

  k_embW<<<256, 512, 0, stream>>>(sentence, pos_tags, We_wrd, We_pos, dan_w0, embW);
  k_scan_a<<<256, 256, 0, stream>>>(embW, cSum);
  k_scan_b<<<2, 256, 0, stream>>>(cSum, cPre);
  k_scan_c<<<256, 256, 0, stream>>>(embW, cPre, csumW);
  k_prepack<<<640, 512, 0, stream>>>(dan_w1, ws_w0, w1_shuf, w0s_shuf, w0pe_shuf);
  k_main<<<638, 512, 0, stream>>>(sp_start, sp_len, csumW, w1_shuf, w0s_shuf, w0pe_shuf,
                                  dan_b0, dan_b1, ws_b0, ws_w1, ws_b1, out);
}